// Round 6
// baseline (262.436 us; speedup 1.0000x reference)
//
#include <hip/hip_runtime.h>
#include <stdint.h>

typedef int v4i __attribute__((ext_vector_type(4)));

#define GLOBAL_AS __attribute__((address_space(1)))
#define LDS_AS __attribute__((address_space(3)))

// Exact replication of reference rounding:
// q = clamp(rint(x / s + z), 0, 255); store (q - zi) as int8.
__device__ __forceinline__ int quant1(float x, float s, float z, int zi) {
    float q = rintf(x / s + z);          // IEEE division + round-half-even, matches np
    q = fminf(fmaxf(q, 0.0f), 255.0f);
    return (int)q - zi;
}

__device__ __forceinline__ unsigned qpack4(float4 v, float s, float z, int zi) {
    unsigned q0 = (unsigned)(quant1(v.x, s, z, zi) & 255);
    unsigned q1 = (unsigned)(quant1(v.y, s, z, zi) & 255);
    unsigned q2 = (unsigned)(quant1(v.z, s, z, zi) & 255);
    unsigned q3 = (unsigned)(quant1(v.w, s, z, zi) & 255);
    return q0 | (q1 << 8) | (q2 << 16) | (q3 << 24);
}

// ---------------- quantize x1 (elementwise, keeps layout [*, K]) ----------------
__global__ __launch_bounds__(256) void quant_lin(const float* __restrict__ x,
                                                 int8_t* __restrict__ out,
                                                 const float* __restrict__ sp,
                                                 const float* __restrict__ zp,
                                                 long n16) {
    float s = sp[0], z = zp[0];
    int zi = (int)rintf(z);
    long i = (long)blockIdx.x * 256 + threadIdx.x;
    if (i >= n16) return;
    const float4* xv = (const float4*)x;
    uint4 w;
    w.x = qpack4(xv[i * 4 + 0], s, z, zi);
    w.y = qpack4(xv[i * 4 + 1], s, z, zi);
    w.z = qpack4(xv[i * 4 + 2], s, z, zi);
    w.w = qpack4(xv[i * 4 + 3], s, z, zi);
    ((uint4*)out)[i] = w;
}

// ------------- quantize x2 [K][N] -> int8 transposed [N][K] -------------
__global__ __launch_bounds__(256) void quant_bt(const float* __restrict__ x,
                                                int8_t* __restrict__ out,
                                                const float* __restrict__ sp,
                                                const float* __restrict__ zp) {
    constexpr int K = 4096, N = 4096;
    float s = sp[0], z = zp[0];
    int zi = (int)rintf(z);
    size_t bin = (size_t)blockIdx.z * K * N;
    int tid = threadIdx.x;
    int bk = tid >> 4;   // 0..15: k-block of 4 rows
    int bn = tid & 15;   // 0..15: n-block of 4 cols
    int k0 = blockIdx.y * 64, n0 = blockIdx.x * 64;
    __shared__ unsigned lds[64][17];
    unsigned o0 = 0, o1 = 0, o2 = 0, o3 = 0;
#pragma unroll
    for (int r = 0; r < 4; ++r) {
        float4 v = *(const float4*)(x + bin + (size_t)(k0 + bk * 4 + r) * N + n0 + bn * 4);
        o0 |= (unsigned)(quant1(v.x, s, z, zi) & 255) << (r * 8);
        o1 |= (unsigned)(quant1(v.y, s, z, zi) & 255) << (r * 8);
        o2 |= (unsigned)(quant1(v.z, s, z, zi) & 255) << (r * 8);
        o3 |= (unsigned)(quant1(v.w, s, z, zi) & 255) << (r * 8);
    }
    lds[bn * 4 + 0][bk] = o0;
    lds[bn * 4 + 1][bk] = o1;
    lds[bn * 4 + 2][bk] = o2;
    lds[bn * 4 + 3][bk] = o3;
    __syncthreads();
    int nl = tid >> 2, ch = tid & 3;
    uint4 w;
    w.x = lds[nl][ch * 4 + 0];
    w.y = lds[nl][ch * 4 + 1];
    w.z = lds[nl][ch * 4 + 2];
    w.w = lds[nl][ch * 4 + 3];
    *(uint4*)(out + bin + (size_t)(n0 + nl) * K + k0 + ch * 16) = w;
}

// ---- int8 GEMM, 256x128 tile, 4 waves/block, 2 blocks/CU, ring-3 LDS ----
// C[b] = Aq[b](MxK) * BqT[b](NxK)^T, mfma_i32_16x16x64_i8, BK=64.
// 256 threads = 4 waves (2Mx2N), per-wave 128x64 output (acc[8][4]).
// LDS 72 KiB/block (ring of 3 slots x [A 16K | B 8K]) -> 2 blocks/CU: the
// two blocks' read/MFMA phases are NOT barrier-locked to each other, so one
// block's ds_read phase overlaps the other's MFMA phase (pipe de-phasing).
// Pipelining: during tile t, issue stage for tile t+2 into slot (t+2)%3
// (= slot(t-1), whose reads drained at t-1's barrier -> no WAR). End-of-tile
// wait = counted vmcnt(6): guarantees tile t+1 landed while t+2's 6 loads
// stay in flight (~2 tile-periods > HBM 900 cyc). Never drains in the loop.
__global__ __launch_bounds__(256, 2) void gemm_i8(const int8_t* __restrict__ A,
                                                  const int8_t* __restrict__ Bt,
                                                  float* __restrict__ C,
                                                  const float* __restrict__ sp1,
                                                  const float* __restrict__ sp2) {
    constexpr int M = 2048, N = 4096, K = 4096;
    constexpr int BM = 256, BN = 128, BK = 64;
    constexpr int NT = K / BK;   // 64
    constexpr int NBN = N / BN;  // 32
    constexpr int SLOT = 24576;  // 16 KiB A + 8 KiB B

    extern __shared__ char smem[];

    int b = blockIdx.z;
    const int8_t* Ab = A + (size_t)b * M * K;
    const int8_t* Bb = Bt + (size_t)b * N * K;
    float* Cb = C + (size_t)b * M * N;

    // XCD-aware swizzle; grid.x = 256, divisible by 8 -> bijective
    int nwg = gridDim.x;
    int wg = blockIdx.x;
    wg = (wg & 7) * (nwg >> 3) + (wg >> 3);
    int by = wg / NBN, bx = wg % NBN;
    int m0 = by * BM, n0 = bx * BN;

    int tid = threadIdx.x;
    int lane = tid & 63, wid = tid >> 6;       // 4 waves
    int wr = wid >> 1, wc = wid & 1;           // 2M x 2N
    int l15 = lane & 15, cb = lane >> 4;

    // ---- per-thread staging pointers (issue cursor, advances BK per ISSUE) ----
    int row0 = tid >> 2, cc0 = tid & 3;        // rows 0..63 per j-step
    int sw0 = cc0 ^ ((row0 >> 1) & 3);         // chunk-XOR swizzle (j-invariant)
    const size_t JSTEP = (size_t)64 * K;       // +64 rows per j
    const int8_t* pAi = Ab + (size_t)(m0 + row0) * K + sw0 * 16;
    const int8_t* pBi = Bb + (size_t)(n0 + row0) * K + sw0 * 16;
    const unsigned dbase = (unsigned)tid * 16;

    // per-lane swizzled byte offsets for fragment ds_reads (B offsets +16K)
    int aoff[8], boff[4];
#pragma unroll
    for (int m = 0; m < 8; ++m) {
        int r = wr * 128 + m * 16 + l15;
        aoff[m] = r * 64 + ((cb ^ ((r >> 1) & 3)) * 16);
    }
#pragma unroll
    for (int n = 0; n < 4; ++n) {
        int r = wc * 64 + n * 16 + l15;
        boff[n] = 16384 + r * 64 + ((cb ^ ((r >> 1) & 3)) * 16);
    }

    v4i zero = {0, 0, 0, 0};
    v4i acc[8][4];
#pragma unroll
    for (int m = 0; m < 8; ++m)
#pragma unroll
        for (int n = 0; n < 4; ++n) acc[m][n] = zero;

// stage next tile (A: 4 loads, B: 2 loads) into slot S; advance cursors
#define ISSUE(S)                                                                       \
    {                                                                                  \
        char* da = smem + (S)*SLOT + dbase;                                            \
        _Pragma("unroll") for (int j = 0; j < 4; ++j)                                  \
            __builtin_amdgcn_global_load_lds((const GLOBAL_AS void*)(pAi + j * JSTEP), \
                                             (LDS_AS void*)(da + j * 4096), 16, 0, 0); \
        char* db = smem + (S)*SLOT + 16384 + dbase;                                    \
        _Pragma("unroll") for (int j = 0; j < 2; ++j)                                  \
            __builtin_amdgcn_global_load_lds((const GLOBAL_AS void*)(pBi + j * JSTEP), \
                                             (LDS_AS void*)(db + j * 4096), 16, 0, 0); \
        pAi += BK;                                                                     \
        pBi += BK;                                                                     \
    }

// one K-tile: 12 ds_reads + optional issue + 32 MFMA, counted waits, 1 barrier
#define TILE(S, DOISSUE, DOWAIT)                                                       \
    {                                                                                  \
        const char* Ar = smem + (S)*SLOT;                                              \
        v4i af[8], bf[4];                                                              \
        _Pragma("unroll") for (int n = 0; n < 4; ++n)                                  \
            bf[n] = *(const v4i*)(Ar + boff[n]);                                       \
        _Pragma("unroll") for (int m = 0; m < 8; ++m)                                  \
            af[m] = *(const v4i*)(Ar + aoff[m]);                                       \
        DOISSUE;                                                                       \
        __builtin_amdgcn_s_setprio(1);                                                 \
        _Pragma("unroll") for (int m = 0; m < 8; ++m)                                  \
            _Pragma("unroll") for (int n = 0; n < 4; ++n)                              \
                acc[m][n] = __builtin_amdgcn_mfma_i32_16x16x64_i8(af[m], bf[n],        \
                                                                  acc[m][n], 0, 0, 0); \
        __builtin_amdgcn_s_setprio(0);                                                 \
        DOWAIT;                                                                        \
    }

#define W6                                                                             \
    asm volatile("s_waitcnt lgkmcnt(0)\n\ts_waitcnt vmcnt(6)" ::: "memory");           \
    __builtin_amdgcn_s_barrier();                                                      \
    asm volatile("" ::: "memory");
#define W0                                                                             \
    asm volatile("s_waitcnt lgkmcnt(0)\n\ts_waitcnt vmcnt(0)" ::: "memory");           \
    __builtin_amdgcn_s_barrier();                                                      \
    asm volatile("" ::: "memory");

    // prologue: stage tiles 0,1 into slots 0,1; ensure tile 0 landed
    ISSUE(0);
    ISSUE(1);
    asm volatile("s_waitcnt vmcnt(6)" ::: "memory");
    __builtin_amdgcn_s_barrier();
    asm volatile("" ::: "memory");

    // main loop: t = 0..59 (slots cycle 0,1,2), issuing t+2
    for (int tt = 0; tt < 60; tt += 3) {
        TILE(0, ISSUE(2), W6)
        TILE(1, ISSUE(0), W6)
        TILE(2, ISSUE(1), W6)
    }
    // t=60,61: last issues (tiles 62,63)
    TILE(0, ISSUE(2), W6)
    TILE(1, ISSUE(0), W6)
    // t=62: no issue; drain so tile 63 is landed
    TILE(2, , W0)
    // t=63: final tile, no wait/barrier needed
    TILE(0, , )

    float sc = sp1[0] * sp2[0];
    int r0 = cb * 4;
#pragma unroll
    for (int m = 0; m < 8; ++m) {
#pragma unroll
        for (int n = 0; n < 4; ++n) {
            float* p = Cb + (size_t)(m0 + wr * 128 + m * 16 + r0) * N +
                       (n0 + wc * 64 + n * 16 + l15);
#pragma unroll
            for (int r = 0; r < 4; ++r) p[(size_t)r * N] = sc * (float)acc[m][n][r];
        }
    }
#undef ISSUE
#undef TILE
#undef W6
#undef W0
}

extern "C" void kernel_launch(void* const* d_in, const int* in_sizes, int n_in,
                              void* d_out, int out_size, void* d_ws, size_t ws_size,
                              hipStream_t stream) {
    const float* x1 = (const float*)d_in[0];
    const float* x2 = (const float*)d_in[1];
    const float* s1 = (const float*)d_in[2];
    const float* z1 = (const float*)d_in[3];
    const float* s2 = (const float*)d_in[4];
    const float* z2 = (const float*)d_in[5];
    float* out = (float*)d_out;

    const int B = 4, M = 2048, K = 4096, N = 4096;
    const size_t ASZ = (size_t)B * M * K;   // int8 bytes for all of x1
    const size_t BSZ = (size_t)B * K * N;   // int8 bytes for all of x2
    dim3 blk(256);

    static int lds_attr_set = 0;
    if (!lds_attr_set) {
        (void)hipFuncSetAttribute((const void*)gemm_i8,
                                  hipFuncAttributeMaxDynamicSharedMemorySize, 73728);
        lds_attr_set = 1;
    }

    if (ws_size >= ASZ + BSZ) {
        int8_t* Aq = (int8_t*)d_ws;
        int8_t* Bq = Aq + ASZ;
        long n16 = (long)(ASZ / 16);
        quant_lin<<<dim3((unsigned)(n16 / 256)), blk, 0, stream>>>(x1, Aq, s1, z1, n16);
        quant_bt<<<dim3(N / 64, K / 64, B), blk, 0, stream>>>(x2, Bq, s2, z2);
        gemm_i8<<<dim3((M / 256) * (N / 128), 1, B), dim3(256), 73728, stream>>>(
            Aq, Bq, out, s1, s2);
    } else {
        const size_t AB = (size_t)M * K, BB = (size_t)K * N;
        int8_t* Aq = (int8_t*)d_ws;
        int8_t* Bq = Aq + AB;
        for (int b = 0; b < B; ++b) {
            long n16 = (long)(AB / 16);
            quant_lin<<<dim3((unsigned)(n16 / 256)), blk, 0, stream>>>(x1 + (size_t)b * AB, Aq, s1, z1, n16);
            quant_bt<<<dim3(N / 64, K / 64, 1), blk, 0, stream>>>(x2 + (size_t)b * BB, Bq, s2, z2);
            gemm_i8<<<dim3((M / 256) * (N / 128), 1, 1), dim3(256), 73728, stream>>>(
                Aq, Bq, out + (size_t)b * M * N, s1, s2);
        }
    }
}